// Round 4
// baseline (139.571 us; speedup 1.0000x reference)
//
#include <hip/hip_runtime.h>

// B=4, S=1024, H=16, D=64 attention, clipped softmax (clip(-8,0), denom clamp).
// Single-pass online softmax, all-MFMA (16x16x32 bf16), fully transposed
// formulation: S^T = K·Q^T, O^T = V^T·P^T. Key rows stored sigma-permuted in
// LDS so the exp'd C-layout P is one shfl_xor(16) away from B-fragment layout
// (no P round-trip through LDS). sVt XOR-swizzled (no padding, no conflicts).
// Block = 128 thr (2 waves x 32 q), k-tile = 128, LDS 34.8KB -> 4 blocks/CU.
#define BB 4
#define SS 1024
#define HH 16
#define DD 64
#define KTL 128
#define NT 128
#define QBLK 64

typedef short bf16x8 __attribute__((ext_vector_type(8)));
typedef float f32x4 __attribute__((ext_vector_type(4)));

#define KP 72    // sK row stride in ushorts (144B; dword stride 36 = conflict-free)

__device__ __forceinline__ unsigned pk2(float a, float b) {   // pack 2 bf16 (round-half-up)
    unsigned ua = __float_as_uint(a) + 0x8000u;
    unsigned ub = __float_as_uint(b) + 0x8000u;
    return (ub & 0xffff0000u) | (ua >> 16);
}
__device__ __forceinline__ unsigned short f2bf(float a) {
    return (unsigned short)((__float_as_uint(a) + 0x8000u) >> 16);
}
__device__ __forceinline__ f32x4 mfma16(bf16x8 a, bf16x8 b, f32x4 c) {
    return __builtin_amdgcn_mfma_f32_16x16x32_bf16(a, b, c, 0, 0, 0);
}
// sigma: LDS row -> global key (permutes within 32-row chunks).
// row = 16a + 4q + b  holds key  8*(q^(b>>1)) + 4a + b.
__device__ __forceinline__ int sigma_row(int r) {
    int a = (r >> 4) & 1, qs = (r >> 2) & 3, b = r & 3;
    return (r & ~31) | ((qs ^ (b >> 1)) << 3) | (a << 2) | b;
}

__global__ __launch_bounds__(NT, 2)
void attn_flash2(const float* __restrict__ q, const float* __restrict__ k,
                 const float* __restrict__ v, float* __restrict__ out) {
    __shared__ unsigned short sK[KTL * KP];      // 18432 B, sigma-permuted key rows
    __shared__ unsigned short sVt[DD * KTL];     // 16384 B, V^T with XOR-swizzled 16B atoms

    const int t = threadIdx.x, lane = t & 63, w = t >> 6;
    const int n16 = lane & 15, quad = lane >> 4;

    // XCD swizzle: all q-tiles of one (b,h) share bx%8 -> same XCD L2
    const int bx = blockIdx.x;               // 1024 blocks
    const int bh = bx & 63, qt = bx >> 6;    // qt 0..15
    const int h = bh & 15, b = bh >> 4;
    const int qbase = qt * QBLK + w * 32;

    const float LOG2E = 1.44269504f;

    // ---- Q B-frags: B[k=d][n=q], q = sub*16+n16, d = ks*32+quad*8+j ----
    bf16x8 qf[2][2];
    #pragma unroll
    for (int s = 0; s < 2; ++s)
      #pragma unroll
      for (int ks = 0; ks < 2; ++ks) {
        const float* p = q + (((size_t)(b * SS + qbase + s * 16 + n16) * HH + h) * DD)
                           + ks * 32 + quad * 8;
        float4 x = ((const float4*)p)[0];
        float4 y = ((const float4*)p)[1];
        bf16x8 f;
        f[0] = (short)f2bf(x.x * 0.125f); f[1] = (short)f2bf(x.y * 0.125f);
        f[2] = (short)f2bf(x.z * 0.125f); f[3] = (short)f2bf(x.w * 0.125f);
        f[4] = (short)f2bf(y.x * 0.125f); f[5] = (short)f2bf(y.y * 0.125f);
        f[6] = (short)f2bf(y.z * 0.125f); f[7] = (short)f2bf(y.w * 0.125f);
        qf[s][ks] = f;
      }

    const size_t bh_off = ((size_t)b * SS * HH + h) * DD;
    const float4* kbase4 = (const float4*)(k + bh_off);
    const float4* vbase4 = (const float4*)(v + bh_off);
    const f32x4 zero = {0.f, 0.f, 0.f, 0.f};

    // online state: q = sub*16 + n16, lane-local (O^T keeps q on n16 everywhere)
    float m[2]  = {-1e30f, -1e30f};
    float su[2] = {0.f, 0.f};
    f32x4 oacc[2][4];   // [sub][dtile]: row d = dt*16+quad*4+r, col q = sub*16+n16
    #pragma unroll
    for (int s = 0; s < 2; ++s)
      #pragma unroll
      for (int dt = 0; dt < 4; ++dt) oacc[s][dt] = zero;

    const int khalf = t & 1, krow2 = t >> 1;     // K staging role
    const int voct = t >> 4, vc = t & 15;        // V staging role

    for (int kt0 = 0; kt0 < SS; kt0 += KTL) {
        // ---- stage K: row r_lds holds key sigma(r_lds); 2 threads/row ----
        #pragma unroll
        for (int p = 0; p < 2; ++p) {
            int row = p * 64 + krow2;
            int gk = sigma_row(row);
            const float4* kp = kbase4 + (size_t)(kt0 + gk) * 256 + khalf * 8;
            float4 r[8];
            #pragma unroll
            for (int i = 0; i < 8; ++i) r[i] = kp[i];
            unsigned short* dst = &sK[row * KP + khalf * 32];
            #pragma unroll
            for (int u = 0; u < 4; ++u) {
                uint4 val;
                val.x = pk2(r[2*u].x, r[2*u].y);
                val.y = pk2(r[2*u].z, r[2*u].w);
                val.z = pk2(r[2*u+1].x, r[2*u+1].y);
                val.w = pk2(r[2*u+1].z, r[2*u+1].w);
                *(uint4*)&dst[u * 8] = val;
            }
        }
        // ---- stage V^T with atom swizzle: atom' = atom ^ ((d>>2)&7) ^ ((d&1)<<2) ----
        #pragma unroll
        for (int p = 0; p < 2; ++p) {
            int o = voct + 8 * p;                 // key octet 0..15
            const float4* vp = vbase4 + (size_t)(kt0 + o * 8) * 256 + vc;
            float4 r[8];
            #pragma unroll
            for (int i = 0; i < 8; ++i) r[i] = vp[i * 256];
            const float* fr = (const float*)r;
            #pragma unroll
            for (int c = 0; c < 4; ++c) {
                int d = 4 * vc + c;
                int atomp = o ^ (vc & 7) ^ ((c & 1) << 2);
                uint4 val;
                val.x = pk2(fr[0*4+c], fr[1*4+c]);
                val.y = pk2(fr[2*4+c], fr[3*4+c]);
                val.z = pk2(fr[4*4+c], fr[5*4+c]);
                val.w = pk2(fr[6*4+c], fr[7*4+c]);
                *(uint4*)&sVt[d * 128 + atomp * 8] = val;
            }
        }
        __syncthreads();

        // ---- QK: S^T = K·Q^T (A = permuted K rows, B = Q) ----
        f32x4 S[2][8];
        #pragma unroll
        for (int ct = 0; ct < 8; ++ct) {
            int base = (ct * 16 + n16) * KP + quad * 8;
            bf16x8 k0 = *(const bf16x8*)&sK[base];
            bf16x8 k1 = *(const bf16x8*)&sK[base + 32];
            S[0][ct] = mfma16(k1, qf[0][1], mfma16(k0, qf[0][0], zero));
            S[1][ct] = mfma16(k1, qf[1][1], mfma16(k0, qf[1][0], zero));
        }

        // ---- online max update (per sub; all state lane-local at q=n16) ----
        #pragma unroll
        for (int s = 0; s < 2; ++s) {
            float tm = S[s][0][0];
            #pragma unroll
            for (int ct = 0; ct < 8; ++ct)
              #pragma unroll
              for (int r = 0; r < 4; ++r) tm = fmaxf(tm, S[s][ct][r]);
            tm = fmaxf(tm, __shfl_xor(tm, 16));
            tm = fmaxf(tm, __shfl_xor(tm, 32));
            float mnew = fmaxf(m[s], tm);
            float al = __builtin_amdgcn_exp2f((m[s] - mnew) * LOG2E);
            m[s] = mnew;
            su[s] *= al;
            #pragma unroll
            for (int dt = 0; dt < 4; ++dt) oacc[s][dt] *= al;
        }

        // ---- exp + pack (P stays in registers, C-layout dword pairs) ----
        unsigned P0[2][8], P1[2][8];
        #pragma unroll
        for (int s = 0; s < 2; ++s)
          #pragma unroll
          for (int ct = 0; ct < 8; ++ct) {
            float x0 = fmaxf(S[s][ct][0] - m[s], -8.0f);
            float x1 = fmaxf(S[s][ct][1] - m[s], -8.0f);
            float x2 = fmaxf(S[s][ct][2] - m[s], -8.0f);
            float x3 = fmaxf(S[s][ct][3] - m[s], -8.0f);
            float e0 = __builtin_amdgcn_exp2f(x0 * LOG2E);
            float e1 = __builtin_amdgcn_exp2f(x1 * LOG2E);
            float e2 = __builtin_amdgcn_exp2f(x2 * LOG2E);
            float e3 = __builtin_amdgcn_exp2f(x3 * LOG2E);
            su[s] += (e0 + e1) + (e2 + e3);
            P0[s][ct] = pk2(e0, e1);
            P1[s][ct] = pk2(e2, e3);
          }

        // ---- PV: O^T += V^T·P^T. P B-frags assembled in-register:
        //      dwords = {P0[2ks] local, P1[2ks] from lane^16, P0[2ks+1], P1[2ks+1]^16}
        #pragma unroll
        for (int s = 0; s < 2; ++s)
          #pragma unroll
          for (int ks = 0; ks < 4; ++ks) {
            union { uint4 u; bf16x8 f; } pf;
            pf.u.x = P0[s][2*ks];
            pf.u.y = (unsigned)__shfl_xor((int)P1[s][2*ks], 16);
            pf.u.z = P0[s][2*ks+1];
            pf.u.w = (unsigned)__shfl_xor((int)P1[s][2*ks+1], 16);
            #pragma unroll
            for (int dt = 0; dt < 4; ++dt) {
                int d = dt * 16 + n16;
                int atomp = (4 * ks + quad) ^ ((d >> 2) & 7) ^ ((d & 1) << 2);
                bf16x8 vf = *(const bf16x8*)&sVt[d * 128 + atomp * 8];
                oacc[s][dt] = mfma16(vf, pf.f, oacc[s][dt]);
            }
          }
        __syncthreads();
    }

    // ---- epilogue: reduce su across quads; clamp; scaled float4 stores ----
    #pragma unroll
    for (int s = 0; s < 2; ++s) {
        su[s] += __shfl_xor(su[s], 16);
        su[s] += __shfl_xor(su[s], 32);
    }
    const float F  = 0.99966460f;   // exp(-exp(-8))
    const float LO = 0.99966454f;   // 1 - exp(-8)
    #pragma unroll
    for (int s = 0; s < 2; ++s) {
        float denom = fminf(fmaxf(su[s] * F, LO), 1024.0f);
        float sc = F / denom;       // lane-local (q = n16): no broadcast needed
        #pragma unroll
        for (int dt = 0; dt < 4; ++dt) {
            float4 val;
            val.x = oacc[s][dt][0] * sc;
            val.y = oacc[s][dt][1] * sc;
            val.z = oacc[s][dt][2] * sc;
            val.w = oacc[s][dt][3] * sc;
            size_t off = ((size_t)(b * SS + qbase + s * 16 + n16) * HH + h) * DD
                       + dt * 16 + quad * 4;
            *(float4*)&out[off] = val;
        }
    }
}

extern "C" void kernel_launch(void* const* d_in, const int* in_sizes, int n_in,
                              void* d_out, int out_size, void* d_ws, size_t ws_size,
                              hipStream_t stream) {
    const float* q = (const float*)d_in[0];
    const float* k = (const float*)d_in[1];
    const float* v = (const float*)d_in[2];
    float* o = (float*)d_out;
    dim3 grid(BB * HH * (SS / QBLK));   // 1024 blocks -> 4 resident/CU
    dim3 block(NT);
    hipLaunchKernelGGL(attn_flash2, grid, block, 0, stream, q, k, v, o);
}